// Round 11
// baseline (840.585 us; speedup 1.0000x reference)
//
#include <hip/hip_runtime.h>
#include <hip/hip_bf16.h>

#define SEQ 2048
#define BATCH 16
#define HID 512
#define OUT_DIM 10
#define NLAYERS 5
#define M_ROWS (SEQ * BATCH)   // 32768
#define N3H (3 * HID)          // 1536
#define GK HID                 // GEMM K

#define CHUNK 32
#define NSEG (SEQ / CHUNK)     // 64

typedef __attribute__((ext_vector_type(8))) _Float16 f16x8;
typedef __attribute__((ext_vector_type(4))) float f32x4;
typedef __attribute__((ext_vector_type(8))) unsigned short u16x8;

__device__ __forceinline__ unsigned short f2h(float x) {
  return __builtin_bit_cast(unsigned short, (_Float16)x);
}
__device__ __forceinline__ float h2f(unsigned short v) {
  return (float)__builtin_bit_cast(_Float16, v);
}
__device__ __forceinline__ float sigm(float x) { return 1.f / (1.f + __expf(-x)); }

// ---------------- f32 -> f16 bulk convert (8 elems/thread) ----------------
__global__ __launch_bounds__(256) void cvt_f32_to_f16(const float* __restrict__ in,
                                                      unsigned short* __restrict__ out) {
  size_t i = ((size_t)blockIdx.x * 256 + threadIdx.x) * 8;
  float4 a = *(const float4*)(in + i);
  float4 b = *(const float4*)(in + i + 4);
  u16x8 r;
  r[0] = f2h(a.x); r[1] = f2h(a.y); r[2] = f2h(a.z); r[3] = f2h(a.w);
  r[4] = f2h(b.x); r[5] = f2h(b.y); r[6] = f2h(b.z); r[7] = f2h(b.w);
  *(u16x8*)(out + i) = r;
}

// ---------------- f16 MFMA GEMM: A-only LDS ring + B direct from L2 ----------------
// C[m][n] = sum_k A[m][k] * W[n][k]. A:[M][512], W:[1536][512] (B^T), C:[M][1536] f16.
// Diagnosis (R10): kernel was LDS-pipe-bound (8 b128 reads + A+B DMA writes per
// wave-K-step ~= 3x the MFMA pipe time). Fix: W is 1.5 MiB = L2-resident, so B
// fragments load global->reg directly (16 full 64B lines per instr), cutting the
// LDS pipe work in half. A stays in a 3-buffer LDS ring with counted vmcnt(6)
// (A(next):2 + B(next):4 in flight across each barrier). K-loop unrolled x2 so
// the B register ring (brA/brB) is statically indexed (no scratch).
__global__ __launch_bounds__(256) void gemm_mfma(const unsigned short* __restrict__ A,
                                                 const unsigned short* __restrict__ W,
                                                 unsigned short* __restrict__ C) {
  // A-ring: 3 x 4096 f16 at [buf*4096]; epilogue C-transpose (128x136 = 17408
  // f16) reuses the whole array.
  __shared__ unsigned short lds[17408];
  const int tid = threadIdx.x;
  const int nwg = (M_ROWS / 128) * (N3H / 128);      // 3072
  const int cpx = nwg / 8;                           // 384 (bijective: 3072 % 8 == 0)
  const int swz = (blockIdx.x % 8) * cpx + blockIdx.x / 8;
  const int bm = swz / (N3H / 128);
  const int bn = swz % (N3H / 128);
  const int lane = tid & 63;
  const int wid = tid >> 6;
  const int wm = (wid >> 1) * 64, wn = (wid & 1) * 64;

  const unsigned short* Ag = A + (size_t)bm * 128 * GK;
  const int s0 = tid, s1 = tid + 256;
  const int r0 = s0 >> 2, c0 = (s0 & 3) * 8;
  const int r1 = s1 >> 2, c1 = (s1 & 3) * 8;

  const int fr = lane & 15;         // fragment row (M for A, N for W)
  const int ko = (lane >> 4) * 8;   // fragment k offset (8 contiguous)

  // per-lane W base: row (bn*128 + wn + nt*16 + fr), 16B slot at k-offset ko
  const unsigned short* Wl = W + (size_t)(bn * 128 + wn + fr) * GK + ko;

  f32x4 acc[4][4];
#pragma unroll
  for (int i = 0; i < 4; ++i)
#pragma unroll
    for (int j = 0; j < 4; ++j) acc[i][j] = (f32x4){0.f, 0.f, 0.f, 0.f};

#define STAGE_A(buf, k0)                                                                            \
  {                                                                                                 \
    __builtin_amdgcn_global_load_lds(                                                               \
        (const __attribute__((address_space(1))) void*)(Ag + (size_t)r0 * GK + (k0) + c0),          \
        (__attribute__((address_space(3))) void*)&lds[(buf) * 4096 + s0 * 8], 16, 0, 0);            \
    __builtin_amdgcn_global_load_lds(                                                               \
        (const __attribute__((address_space(1))) void*)(Ag + (size_t)r1 * GK + (k0) + c1),          \
        (__attribute__((address_space(3))) void*)&lds[(buf) * 4096 + s1 * 8], 16, 0, 0);            \
  }
#define LOADB(dst, kk)                                                                              \
  {                                                                                                 \
    dst##0 = *(const f16x8*)(Wl + 0 * 16 * GK + (kk));                                              \
    dst##1 = *(const f16x8*)(Wl + 1 * 16 * GK + (kk));                                              \
    dst##2 = *(const f16x8*)(Wl + 2 * 16 * GK + (kk));                                              \
    dst##3 = *(const f16x8*)(Wl + 3 * 16 * GK + (kk));                                              \
  }
#define DOMFMA(bv)                                                                                  \
  {                                                                                                 \
    f16x8 af[4];                                                                                    \
    _Pragma("unroll") for (int t = 0; t < 4; ++t)                                                   \
        af[t] = *(const f16x8*)&lds[abase + (wm + t * 16 + fr) * 32 + ko];                          \
    _Pragma("unroll") for (int mt = 0; mt < 4; ++mt) {                                              \
      acc[mt][0] = __builtin_amdgcn_mfma_f32_16x16x32_f16(af[mt], bv##0, acc[mt][0], 0, 0, 0);      \
      acc[mt][1] = __builtin_amdgcn_mfma_f32_16x16x32_f16(af[mt], bv##1, acc[mt][1], 0, 0, 0);      \
      acc[mt][2] = __builtin_amdgcn_mfma_f32_16x16x32_f16(af[mt], bv##2, acc[mt][2], 0, 0, 0);      \
      acc[mt][3] = __builtin_amdgcn_mfma_f32_16x16x32_f16(af[mt], bv##3, acc[mt][3], 0, 0, 0);      \
    }                                                                                               \
  }

  f16x8 brA0, brA1, brA2, brA3, brB0, brB1, brB2, brB3;
  STAGE_A(0, 0);
  STAGE_A(1, 32);
  LOADB(brA, 0);

  int buf = 0;  // LDS buffer holding K-step k0
#pragma unroll 1
  for (int kt2 = 0; kt2 < 8; ++kt2) {
    const int k0 = kt2 * 2;
    // ---- even sub-step: compute k0 (A from buf, B from brA) ----
    asm volatile("s_waitcnt vmcnt(6)" ::: "memory");   // A(k0) staged; 6 newer stay in flight
    __builtin_amdgcn_s_barrier();
    __builtin_amdgcn_sched_barrier(0);
    if (k0 + 2 < 16) STAGE_A((buf + 2) % 3, (k0 + 2) * 32);
    LOADB(brB, (k0 + 1) * 32);                         // k0+1 <= 15 always
    {
      const int abase = buf * 4096;
      DOMFMA(brA);
    }
    // ---- odd sub-step: compute k0+1 (A from buf+1, B from brB) ----
    asm volatile("s_waitcnt vmcnt(6)" ::: "memory");
    __builtin_amdgcn_s_barrier();
    __builtin_amdgcn_sched_barrier(0);
    if (k0 + 3 < 16) STAGE_A((buf + 3) % 3, (k0 + 3) * 32);
    if (k0 + 2 < 16) LOADB(brA, (k0 + 2) * 32);
    {
      const int abase = ((buf + 1) % 3) * 4096;
      DOMFMA(brB);
    }
    buf = (buf + 2) % 3;
  }
#undef STAGE_A
#undef LOADB
#undef DOMFMA

  // ---- coalesced C-write via LDS transpose (row stride padded to 136) ----
  __syncthreads();  // drains everything; all buffers dead
  unsigned short* cl = &lds[0];
  const int er = (lane >> 4) * 4;   // C/D layout: col=lane&15, row=(lane>>4)*4+reg
#pragma unroll
  for (int mt = 0; mt < 4; ++mt)
#pragma unroll
    for (int nt = 0; nt < 4; ++nt) {
      const int row = wm + mt * 16 + er;
      const int col = wn + nt * 16 + fr;
#pragma unroll
      for (int j = 0; j < 4; ++j) cl[(row + j) * 136 + col] = f2h(acc[mt][nt][j]);
    }
  __syncthreads();
  unsigned short* Cb = C + (size_t)bm * 128 * N3H + bn * 128;
#pragma unroll
  for (int i = 0; i < 8; ++i) {
    int flat = i * 2048 + tid * 8;
    int r = flat >> 7, c = flat & 127;
    *(u16x8*)(Cb + (size_t)r * N3H + c) = *(const u16x8*)&cl[r * 136 + c];
  }
}

// ---------------- Fused single-pass SRU scan (decoupled lookback) ----------------
// Grid: 64 segments x 16 batch = 1024 blocks; 256 thr x 2h = 512 chains/block.
// Protocol: per (segment, chain) publish (F, C) packed in ONE 64-bit word via
// atomicExch; F stored NEGATED so the low word's sign bit doubles as the
// "published" tag. FC epoch buffer is pre-zeroed (one memset for all layers).
__global__ __launch_bounds__(256, 4) void sru_scan_fused(
    const unsigned short* __restrict__ U,     // [L][B][3H] f16: xt | zf | zr
    const float* __restrict__ bias,           // [2H]
    unsigned long long* __restrict__ FC,      // [NSEG][B][H] packed, pre-zeroed
    unsigned short* hb) {                     // [L][B][H] f16, updated in place
  const int s = blockIdx.x >> 4;
  const int b = blockIdx.x & 15;
  const int h0 = threadIdx.x << 1;
  const float bf0 = bias[h0], bf1 = bias[h0 + 1];
  const float br0 = bias[HID + h0], br1 = bias[HID + h0 + 1];

  const size_t rowstep = (size_t)BATCH * N3H;
  const unsigned short* Up = U + ((size_t)(s * CHUNK) * BATCH + b) * N3H + h0;

  // ---- phase 1: local (F, C | c0=0); retain packed (f16 f, f16 xt) per step
  unsigned fx0[CHUNK], fx1[CHUNK];
  float F0 = 1.f, F1 = 1.f, c0 = 0.f, c1 = 0.f;
#pragma unroll
  for (int i = 0; i < CHUNK; ++i) {
    const unsigned short* p = Up + (size_t)i * rowstep;
    unsigned xt = *(const unsigned*)(p);
    unsigned zf = *(const unsigned*)(p + HID);
    unsigned short fh0 = f2h(sigm(h2f((unsigned short)zf) + bf0));
    unsigned short fh1 = f2h(sigm(h2f((unsigned short)(zf >> 16)) + bf1));
    float f0 = h2f(fh0), f1 = h2f(fh1);
    c0 = f0 * c0 + (1.f - f0) * h2f((unsigned short)xt);
    c1 = f1 * c1 + (1.f - f1) * h2f((unsigned short)(xt >> 16));
    F0 *= f0; F1 *= f1;
    fx0[i] = (xt & 0xffffu) | ((unsigned)fh0 << 16);
    fx1[i] = (xt >> 16) | ((unsigned)fh1 << 16);
  }

  // ---- publish (single-word atomic; no fence needed)
  const size_t ch = ((size_t)s * BATCH + b) * HID + h0;
  atomicExch(&FC[ch],
             ((unsigned long long)__builtin_bit_cast(unsigned, c0) << 32) |
                 __builtin_bit_cast(unsigned, -F0));
  atomicExch(&FC[ch + 1],
             ((unsigned long long)__builtin_bit_cast(unsigned, c1) << 32) |
                 __builtin_bit_cast(unsigned, -F1));

  // ---- lookback: c_in = sum_{j<s} C_j * prod_{j<k<s} F_k
  float ci0 = 0.f, ci1 = 0.f, P0 = 1.f, P1 = 1.f;
  for (int j = s - 1; j >= 0; --j) {
    const size_t cj = ((size_t)j * BATCH + b) * HID + h0;
    unsigned long long v0, v1;
    do { v0 = atomicAdd(&FC[cj], 0ULL); } while (!(v0 & 0x80000000ULL));
    do { v1 = atomicAdd(&FC[cj + 1], 0ULL); } while (!(v1 & 0x80000000ULL));
    float Fj0 = -__builtin_bit_cast(float, (unsigned)v0);
    float Cj0 = __builtin_bit_cast(float, (unsigned)(v0 >> 32));
    float Fj1 = -__builtin_bit_cast(float, (unsigned)v1);
    float Cj1 = __builtin_bit_cast(float, (unsigned)(v1 >> 32));
    ci0 += P0 * Cj0; P0 *= Fj0;
    ci1 += P1 * Cj1; P1 *= Fj1;
    if (P0 == 0.f && P1 == 0.f) break;   // product underflow: rest contributes 0
  }

  // ---- phase 3: replay with carry; read zr + x, write h in place
  float cc0 = ci0, cc1 = ci1;
  const size_t hstep = (size_t)BATCH * HID;
  unsigned short* hp = hb + ((size_t)(s * CHUNK) * BATCH + b) * HID + h0;
#pragma unroll
  for (int i = 0; i < CHUNK; ++i) {
    unsigned zr = *(const unsigned*)(Up + (size_t)i * rowstep + 2 * HID);
    unsigned xv = *(const unsigned*)(hp + (size_t)i * hstep);
    float f0 = h2f((unsigned short)(fx0[i] >> 16));
    float f1 = h2f((unsigned short)(fx1[i] >> 16));
    cc0 = f0 * cc0 + (1.f - f0) * h2f((unsigned short)fx0[i]);
    cc1 = f1 * cc1 + (1.f - f1) * h2f((unsigned short)fx1[i]);
    float r0 = sigm(h2f((unsigned short)zr) + br0);
    float r1 = sigm(h2f((unsigned short)(zr >> 16)) + br1);
    float hn0 = r0 * cc0 + (1.f - r0) * h2f((unsigned short)xv);
    float hn1 = r1 * cc1 + (1.f - r1) * h2f((unsigned short)(xv >> 16));
    *(unsigned*)(hp + (size_t)i * hstep) = (unsigned)f2h(hn0) | ((unsigned)f2h(hn1) << 16);
  }
}

// ---------------- FC head (f16 H, f32 math) ----------------
#define FCR 16
__global__ __launch_bounds__(256) void fc_kernel(const unsigned short* __restrict__ H,
                                                 const float* __restrict__ W,
                                                 const float* __restrict__ bv,
                                                 float* __restrict__ out) {
  __shared__ float hs[FCR][516];
  __shared__ float ws[OUT_DIM][516];
  const int tid = threadIdx.x;
  const size_t m0 = (size_t)blockIdx.x * FCR;
#pragma unroll
  for (int i = 0; i < 4; ++i) {
    int f = tid + i * 256;
    int row = f >> 6;     // 0..15
    int kq = f & 63;      // 8-elem group
    u16x8 v = *(const u16x8*)(H + (m0 + row) * 512 + kq * 8);
#pragma unroll
    for (int j = 0; j < 8; ++j) hs[row][kq * 8 + j] = h2f(v[j]);
  }
#pragma unroll
  for (int i = 0; i < 5; ++i) {
    int f = tid + i * 256;
    int row = f >> 7;     // 0..9
    int kq = f & 127;
    float4 v = *(const float4*)(W + row * 512 + kq * 4);
    *(float4*)&ws[row][kq * 4] = v;
  }
  __syncthreads();
  if (tid < FCR * OUT_DIM) {
    int row = tid / OUT_DIM;
    int o = tid - row * OUT_DIM;
    float acc = bv[o];
#pragma unroll 8
    for (int k = 0; k < 512; ++k) acc += hs[row][k] * ws[o][k];
    out[(m0 + row) * OUT_DIM + o] = acc;
  }
}

extern "C" void kernel_launch(void* const* d_in, const int* in_sizes, int n_in,
                              void* d_out, int out_size, void* d_ws, size_t ws_size,
                              hipStream_t stream) {
  const float* x   = (const float*)d_in[0];  // [2048][16][512]
  const float* Ws  = (const float*)d_in[1];  // [5][1536][512]
  const float* bs  = (const float*)d_in[2];  // [5][1024]
  const float* fcW = (const float*)d_in[3];  // [10][512]
  const float* fcb = (const float*)d_in[4];  // [10]
  float* out = (float*)d_out;

  char* ws = (char*)d_ws;
  const size_t MiB = 1024 * 1024;
  unsigned short* Ub = (unsigned short*)ws;                  // 96 MiB: [M][1536] f16
  unsigned short* hb = (unsigned short*)(ws + 96 * MiB);     // 32 MiB: [M][512] f16
  unsigned short* Wh = (unsigned short*)(ws + 128 * MiB);    // 7.5 MiB f16 weights
  unsigned long long* FC = (unsigned long long*)(ws + 136 * MiB);  // 20 MiB: 5 epochs
  // total 156 MiB <= 256 MiB workspace

  // one-time converts + single lookback-buffer clear for ALL layers
  hipMemsetAsync(FC, 0, (size_t)NLAYERS * NSEG * BATCH * HID * 8, stream);
  cvt_f32_to_f16<<<(NLAYERS * N3H * HID) / (256 * 8), 256, 0, stream>>>(Ws, Wh);
  cvt_f32_to_f16<<<(M_ROWS * HID) / (256 * 8), 256, 0, stream>>>(x, hb);

  for (int l = 0; l < NLAYERS; ++l) {
    gemm_mfma<<<(M_ROWS / 128) * (N3H / 128), 256, 0, stream>>>(
        hb, Wh + (size_t)l * N3H * HID, Ub);
    sru_scan_fused<<<NSEG * BATCH, 256, 0, stream>>>(
        Ub, bs + (size_t)l * 2 * HID,
        FC + (size_t)l * NSEG * BATCH * HID, hb);
  }
  fc_kernel<<<M_ROWS / FCR, 256, 0, stream>>>(hb, fcW, fcb, out);
}

// Round 12
// 612.247 us; speedup vs baseline: 1.3729x; 1.3729x over previous
//
#include <hip/hip_runtime.h>
#include <hip/hip_bf16.h>

#define SEQ 2048
#define BATCH 16
#define HID 512
#define OUT_DIM 10
#define NLAYERS 5
#define M_ROWS (SEQ * BATCH)   // 32768
#define N3H (3 * HID)          // 1536
#define GK HID                 // GEMM K

#define CHUNK 32
#define NSEG (SEQ / CHUNK)     // 64

typedef __attribute__((ext_vector_type(8))) _Float16 f16x8;
typedef __attribute__((ext_vector_type(4))) float f32x4;
typedef __attribute__((ext_vector_type(8))) unsigned short u16x8;

__device__ __forceinline__ unsigned short f2h(float x) {
  return __builtin_bit_cast(unsigned short, (_Float16)x);
}
__device__ __forceinline__ float h2f(unsigned short v) {
  return (float)__builtin_bit_cast(_Float16, v);
}
__device__ __forceinline__ float sigm(float x) { return 1.f / (1.f + __expf(-x)); }

// ---------------- f32 -> f16 bulk convert (8 elems/thread) ----------------
__global__ __launch_bounds__(256) void cvt_f32_to_f16(const float* __restrict__ in,
                                                      unsigned short* __restrict__ out) {
  size_t i = ((size_t)blockIdx.x * 256 + threadIdx.x) * 8;
  float4 a = *(const float4*)(in + i);
  float4 b = *(const float4*)(in + i + 4);
  u16x8 r;
  r[0] = f2h(a.x); r[1] = f2h(a.y); r[2] = f2h(a.z); r[3] = f2h(a.w);
  r[4] = f2h(b.x); r[5] = f2h(b.y); r[6] = f2h(b.z); r[7] = f2h(b.w);
  *(u16x8*)(out + i) = r;
}

// ---------------- f16 MFMA GEMM: 3-buffer ring, counted vmcnt(4) (R10, 71us) ----------------
// C[m][n] = sum_k A[m][k] * B[n][k]. A:[M][512], B:[1536][512] (B^T), C:[M][1536] f16.
__global__ __launch_bounds__(256) void gemm_mfma(const unsigned short* __restrict__ A,
                                                 const unsigned short* __restrict__ B,
                                                 unsigned short* __restrict__ C) {
  __shared__ unsigned short lds[3][8192];
  const int tid = threadIdx.x;
  const int nwg = (M_ROWS / 128) * (N3H / 128);      // 3072
  const int cpx = nwg / 8;                           // 384 (bijective: 3072 % 8 == 0)
  const int swz = (blockIdx.x % 8) * cpx + blockIdx.x / 8;
  const int bm = swz / (N3H / 128);
  const int bn = swz % (N3H / 128);
  const int lane = tid & 63;
  const int wid = tid >> 6;
  const int wm = (wid >> 1) * 64, wn = (wid & 1) * 64;

  const unsigned short* Ag = A + (size_t)bm * 128 * GK;
  const unsigned short* Bg = B + (size_t)bn * 128 * GK;

  const int s0 = tid, s1 = tid + 256;
  const int r0 = s0 >> 2, c0 = (s0 & 3) * 8;
  const int r1 = s1 >> 2, c1 = (s1 & 3) * 8;

  const int fr = lane & 15;         // fragment row (M for A, N for B)
  const int ko = (lane >> 4) * 8;   // fragment k offset (8 contiguous)

  f32x4 acc[4][4];
#pragma unroll
  for (int i = 0; i < 4; ++i)
#pragma unroll
    for (int j = 0; j < 4; ++j) acc[i][j] = (f32x4){0.f, 0.f, 0.f, 0.f};

#define STAGE(buf, k0)                                                                              \
  {                                                                                                 \
    __builtin_amdgcn_global_load_lds(                                                               \
        (const __attribute__((address_space(1))) void*)(Ag + (size_t)r0 * GK + (k0) + c0),          \
        (__attribute__((address_space(3))) void*)&lds[buf][s0 * 8], 16, 0, 0);                      \
    __builtin_amdgcn_global_load_lds(                                                               \
        (const __attribute__((address_space(1))) void*)(Ag + (size_t)r1 * GK + (k0) + c1),          \
        (__attribute__((address_space(3))) void*)&lds[buf][s1 * 8], 16, 0, 0);                      \
    __builtin_amdgcn_global_load_lds(                                                               \
        (const __attribute__((address_space(1))) void*)(Bg + (size_t)r0 * GK + (k0) + c0),          \
        (__attribute__((address_space(3))) void*)&lds[buf][4096 + s0 * 8], 16, 0, 0);               \
    __builtin_amdgcn_global_load_lds(                                                               \
        (const __attribute__((address_space(1))) void*)(Bg + (size_t)r1 * GK + (k0) + c1),          \
        (__attribute__((address_space(3))) void*)&lds[buf][4096 + s1 * 8], 16, 0, 0);               \
  }

  STAGE(0, 0);
  STAGE(1, 32);
#pragma unroll 1
  for (int kt = 0; kt < 16; ++kt) {
    if (kt < 15) {
      asm volatile("s_waitcnt vmcnt(4)" ::: "memory");
    } else {
      asm volatile("s_waitcnt vmcnt(0)" ::: "memory");
    }
    __builtin_amdgcn_s_barrier();
    __builtin_amdgcn_sched_barrier(0);   // pin: nothing moves above the barrier
    if (kt + 2 < 16) STAGE((kt + 2) % 3, (kt + 2) * 32);
    const int cb = kt % 3;
    f16x8 af[4], bfr[4];
#pragma unroll
    for (int t = 0; t < 4; ++t) {
      af[t]  = *(const f16x8*)&lds[cb][(wm + t * 16 + fr) * 32 + ko];
      bfr[t] = *(const f16x8*)&lds[cb][4096 + (wn + t * 16 + fr) * 32 + ko];
    }
#pragma unroll
    for (int mt = 0; mt < 4; ++mt)
#pragma unroll
      for (int nt = 0; nt < 4; ++nt)
        acc[mt][nt] = __builtin_amdgcn_mfma_f32_16x16x32_f16(af[mt], bfr[nt], acc[mt][nt], 0, 0, 0);
  }
#undef STAGE

  // ---- coalesced C-write via LDS transpose (row stride padded to 136) ----
  __syncthreads();  // all waves done reading buffers
  unsigned short* cl = &lds[0][0];
  const int er = (lane >> 4) * 4;   // C/D layout: col=lane&15, row=(lane>>4)*4+reg
#pragma unroll
  for (int mt = 0; mt < 4; ++mt)
#pragma unroll
    for (int nt = 0; nt < 4; ++nt) {
      const int row = wm + mt * 16 + er;
      const int col = wn + nt * 16 + fr;
#pragma unroll
      for (int j = 0; j < 4; ++j) cl[(row + j) * 136 + col] = f2h(acc[mt][nt][j]);
    }
  __syncthreads();
  unsigned short* Cb = C + (size_t)bm * 128 * N3H + bn * 128;
#pragma unroll
  for (int i = 0; i < 8; ++i) {
    int flat = i * 2048 + tid * 8;
    int r = flat >> 7, c = flat & 127;
    *(u16x8*)(Cb + (size_t)r * N3H + c) = *(const u16x8*)&cl[r * 136 + c];
  }
}

// ---------------- Fused single-pass SRU scan (decoupled lookback) ----------------
// Grid: 64 segments x 16 batch = 1024 blocks; 256 thr x 2h = 512 chains/block.
// Publish (F, C) packed in ONE 64-bit word via atomicExch; F stored NEGATED so
// the low word's sign bit doubles as the "published" tag. FC pre-zeroed (one
// memset covers all 5 layer epochs).
// Lookback early-exit: break when P < 1e-5 (remaining carry contribution
// <= 1e-5 * |C| << f16 ulp of h). The old P==0 test required f32 underflow
// (~150 halvings) and never fired -> full 63-deep walks of polling atomics.
__global__ __launch_bounds__(256, 4) void sru_scan_fused(
    const unsigned short* __restrict__ U,     // [L][B][3H] f16: xt | zf | zr
    const float* __restrict__ bias,           // [2H]
    unsigned long long* __restrict__ FC,      // [NSEG][B][H] packed, pre-zeroed
    unsigned short* hb) {                     // [L][B][H] f16, updated in place
  const int s = blockIdx.x >> 4;
  const int b = blockIdx.x & 15;
  const int h0 = threadIdx.x << 1;
  const float bf0 = bias[h0], bf1 = bias[h0 + 1];
  const float br0 = bias[HID + h0], br1 = bias[HID + h0 + 1];

  const size_t rowstep = (size_t)BATCH * N3H;
  const unsigned short* Up = U + ((size_t)(s * CHUNK) * BATCH + b) * N3H + h0;

  // ---- phase 1: local (F, C | c0=0); retain packed (f16 f, f16 xt) per step
  unsigned fx0[CHUNK], fx1[CHUNK];
  float F0 = 1.f, F1 = 1.f, c0 = 0.f, c1 = 0.f;
#pragma unroll
  for (int i = 0; i < CHUNK; ++i) {
    const unsigned short* p = Up + (size_t)i * rowstep;
    unsigned xt = *(const unsigned*)(p);
    unsigned zf = *(const unsigned*)(p + HID);
    unsigned short fh0 = f2h(sigm(h2f((unsigned short)zf) + bf0));
    unsigned short fh1 = f2h(sigm(h2f((unsigned short)(zf >> 16)) + bf1));
    float f0 = h2f(fh0), f1 = h2f(fh1);
    c0 = f0 * c0 + (1.f - f0) * h2f((unsigned short)xt);
    c1 = f1 * c1 + (1.f - f1) * h2f((unsigned short)(xt >> 16));
    F0 *= f0; F1 *= f1;
    fx0[i] = (xt & 0xffffu) | ((unsigned)fh0 << 16);
    fx1[i] = (xt >> 16) | ((unsigned)fh1 << 16);
  }

  // ---- publish (single-word atomic; no fence needed)
  const size_t ch = ((size_t)s * BATCH + b) * HID + h0;
  atomicExch(&FC[ch],
             ((unsigned long long)__builtin_bit_cast(unsigned, c0) << 32) |
                 __builtin_bit_cast(unsigned, -F0));
  atomicExch(&FC[ch + 1],
             ((unsigned long long)__builtin_bit_cast(unsigned, c1) << 32) |
                 __builtin_bit_cast(unsigned, -F1));

  // ---- lookback: c_in = sum_{j<s} C_j * prod_{j<k<s} F_k
  float ci0 = 0.f, ci1 = 0.f, P0 = 1.f, P1 = 1.f;
  for (int j = s - 1; j >= 0; --j) {
    const size_t cj = ((size_t)j * BATCH + b) * HID + h0;
    unsigned long long v0, v1;
    do { v0 = atomicAdd(&FC[cj], 0ULL); } while (!(v0 & 0x80000000ULL));
    do { v1 = atomicAdd(&FC[cj + 1], 0ULL); } while (!(v1 & 0x80000000ULL));
    float Fj0 = -__builtin_bit_cast(float, (unsigned)v0);
    float Cj0 = __builtin_bit_cast(float, (unsigned)(v0 >> 32));
    float Fj1 = -__builtin_bit_cast(float, (unsigned)v1);
    float Cj1 = __builtin_bit_cast(float, (unsigned)(v1 >> 32));
    ci0 += P0 * Cj0; P0 *= Fj0;
    ci1 += P1 * Cj1; P1 *= Fj1;
    if (P0 < 1e-5f && P1 < 1e-5f) break;   // remaining contribution < f16 ulp
  }

  // ---- phase 3: replay with carry; read zr + x, write h in place
  float cc0 = ci0, cc1 = ci1;
  const size_t hstep = (size_t)BATCH * HID;
  unsigned short* hp = hb + ((size_t)(s * CHUNK) * BATCH + b) * HID + h0;
#pragma unroll
  for (int i = 0; i < CHUNK; ++i) {
    unsigned zr = *(const unsigned*)(Up + (size_t)i * rowstep + 2 * HID);
    unsigned xv = *(const unsigned*)(hp + (size_t)i * hstep);
    float f0 = h2f((unsigned short)(fx0[i] >> 16));
    float f1 = h2f((unsigned short)(fx1[i] >> 16));
    cc0 = f0 * cc0 + (1.f - f0) * h2f((unsigned short)fx0[i]);
    cc1 = f1 * cc1 + (1.f - f1) * h2f((unsigned short)fx1[i]);
    float r0 = sigm(h2f((unsigned short)zr) + br0);
    float r1 = sigm(h2f((unsigned short)(zr >> 16)) + br1);
    float hn0 = r0 * cc0 + (1.f - r0) * h2f((unsigned short)xv);
    float hn1 = r1 * cc1 + (1.f - r1) * h2f((unsigned short)(xv >> 16));
    *(unsigned*)(hp + (size_t)i * hstep) = (unsigned)f2h(hn0) | ((unsigned)f2h(hn1) << 16);
  }
}

// ---------------- FC head (f16 H, f32 math) ----------------
#define FCR 16
__global__ __launch_bounds__(256) void fc_kernel(const unsigned short* __restrict__ H,
                                                 const float* __restrict__ W,
                                                 const float* __restrict__ bv,
                                                 float* __restrict__ out) {
  __shared__ float hs[FCR][516];
  __shared__ float ws[OUT_DIM][516];
  const int tid = threadIdx.x;
  const size_t m0 = (size_t)blockIdx.x * FCR;
#pragma unroll
  for (int i = 0; i < 4; ++i) {
    int f = tid + i * 256;
    int row = f >> 6;     // 0..15
    int kq = f & 63;      // 8-elem group
    u16x8 v = *(const u16x8*)(H + (m0 + row) * 512 + kq * 8);
#pragma unroll
    for (int j = 0; j < 8; ++j) hs[row][kq * 8 + j] = h2f(v[j]);
  }
#pragma unroll
  for (int i = 0; i < 5; ++i) {
    int f = tid + i * 256;
    int row = f >> 7;     // 0..9
    int kq = f & 127;
    float4 v = *(const float4*)(W + row * 512 + kq * 4);
    *(float4*)&ws[row][kq * 4] = v;
  }
  __syncthreads();
  if (tid < FCR * OUT_DIM) {
    int row = tid / OUT_DIM;
    int o = tid - row * OUT_DIM;
    float acc = bv[o];
#pragma unroll 8
    for (int k = 0; k < 512; ++k) acc += hs[row][k] * ws[o][k];
    out[(m0 + row) * OUT_DIM + o] = acc;
  }
}

extern "C" void kernel_launch(void* const* d_in, const int* in_sizes, int n_in,
                              void* d_out, int out_size, void* d_ws, size_t ws_size,
                              hipStream_t stream) {
  const float* x   = (const float*)d_in[0];  // [2048][16][512]
  const float* Ws  = (const float*)d_in[1];  // [5][1536][512]
  const float* bs  = (const float*)d_in[2];  // [5][1024]
  const float* fcW = (const float*)d_in[3];  // [10][512]
  const float* fcb = (const float*)d_in[4];  // [10]
  float* out = (float*)d_out;

  char* ws = (char*)d_ws;
  const size_t MiB = 1024 * 1024;
  unsigned short* Ub = (unsigned short*)ws;                  // 96 MiB: [M][1536] f16
  unsigned short* hb = (unsigned short*)(ws + 96 * MiB);     // 32 MiB: [M][512] f16
  unsigned short* Wh = (unsigned short*)(ws + 128 * MiB);    // 7.5 MiB f16 weights
  unsigned long long* FC = (unsigned long long*)(ws + 136 * MiB);  // 20 MiB: 5 epochs
  // total 156 MiB <= 256 MiB workspace

  // one-time converts + single lookback-buffer clear for ALL layers
  hipMemsetAsync(FC, 0, (size_t)NLAYERS * NSEG * BATCH * HID * 8, stream);
  cvt_f32_to_f16<<<(NLAYERS * N3H * HID) / (256 * 8), 256, 0, stream>>>(Ws, Wh);
  cvt_f32_to_f16<<<(M_ROWS * HID) / (256 * 8), 256, 0, stream>>>(x, hb);

  for (int l = 0; l < NLAYERS; ++l) {
    gemm_mfma<<<(M_ROWS / 128) * (N3H / 128), 256, 0, stream>>>(
        hb, Wh + (size_t)l * N3H * HID, Ub);
    sru_scan_fused<<<NSEG * BATCH, 256, 0, stream>>>(
        Ub, bs + (size_t)l * 2 * HID,
        FC + (size_t)l * NSEG * BATCH * HID, hb);
  }
  fc_kernel<<<M_ROWS / FCR, 256, 0, stream>>>(hb, fcW, fcb, out);
}